// Round 1
// baseline (312.467 us; speedup 1.0000x reference)
//
#include <hip/hip_runtime.h>

#define NROWS 32768
#define DIM 32
#define KCODES 8192
#define ROWS_PER_BLOCK 64
#define WAVES 8
#define KSLICE (KCODES / WAVES)  // 1024
#define NBLOCKS (NROWS / ROWS_PER_BLOCK)  // 512

__device__ __forceinline__ float dot4(const float4& a, const float4& b) {
    return fmaf(a.w, b.w, fmaf(a.z, b.z, fmaf(a.y, b.y, a.x * b.x)));
}

__global__ __launch_bounds__(WAVES * 64, 1) void vq_main(
    const float* __restrict__ inputs,
    const float* __restrict__ emb,
    float* __restrict__ out_q,     // [NROWS*DIM]
    float* __restrict__ out_idx,   // [NROWS], indices stored as float
    float* __restrict__ ws_partial // [NBLOCKS] per-block loss partial sums
) {
    const int lane = threadIdx.x & 63;
    const int wave = __builtin_amdgcn_readfirstlane(threadIdx.x >> 6);
    const int row  = blockIdx.x * ROWS_PER_BLOCK + lane;

    // Load this lane's input row (32 floats) into registers.
    const float4* xin = reinterpret_cast<const float4*>(inputs + (size_t)row * DIM);
    float4 x0 = xin[0], x1 = xin[1], x2 = xin[2], x3 = xin[3];
    float4 x4 = xin[4], x5 = xin[5], x6 = xin[6], x7 = xin[7];

    const float4* e4 = reinterpret_cast<const float4*>(emb);

    float bestv = -3.0e38f;
    int   besti = 0;
    const int k0 = wave * KSLICE;

    // k is wave-uniform -> embedding reads should be scalar (s_load) from L2.
    #pragma unroll 2
    for (int k = k0; k < k0 + KSLICE; ++k) {
        const float4* ep = e4 + ((size_t)k << 3);
        float4 a0 = ep[0], a1 = ep[1], a2 = ep[2], a3 = ep[3];
        float4 a4 = ep[4], a5 = ep[5], a6 = ep[6], a7 = ep[7];
        float d0 = dot4(x0, a0);
        float d1 = dot4(x1, a1);
        float d2 = dot4(x2, a2);
        float d3 = dot4(x3, a3);
        float d4 = dot4(x4, a4);
        float d5 = dot4(x5, a5);
        float d6 = dot4(x6, a6);
        float d7 = dot4(x7, a7);
        float dot = ((d0 + d1) + (d2 + d3)) + ((d4 + d5) + (d6 + d7));
        // strict > keeps first occurrence (lowest k) on exact ties
        if (dot > bestv) { bestv = dot; besti = k; }
    }

    __shared__ float svals[WAVES][ROWS_PER_BLOCK];
    __shared__ int   sidxs[WAVES][ROWS_PER_BLOCK];
    svals[wave][lane] = bestv;
    sidxs[wave][lane] = besti;
    __syncthreads();

    if (wave == 0) {
        float bv = svals[0][lane];
        int   bi = sidxs[0][lane];
        #pragma unroll
        for (int w = 1; w < WAVES; ++w) {
            float v = svals[w][lane];
            int   i = sidxs[w][lane];
            // strict > : on equal values keep lower wave == lower k (first occurrence)
            if (v > bv) { bv = v; bi = i; }
        }

        // Gather the winning code row, write quantized output, accumulate loss.
        const float4* eq = e4 + ((size_t)bi << 3);
        float4* oq = reinterpret_cast<float4*>(out_q + (size_t)row * DIM);
        float s = 0.0f;
        {
            float4 q, x;
            q = eq[0]; x = x0; oq[0] = q;
            s += (q.x-x.x)*(q.x-x.x) + (q.y-x.y)*(q.y-x.y) + (q.z-x.z)*(q.z-x.z) + (q.w-x.w)*(q.w-x.w);
            q = eq[1]; x = x1; oq[1] = q;
            s += (q.x-x.x)*(q.x-x.x) + (q.y-x.y)*(q.y-x.y) + (q.z-x.z)*(q.z-x.z) + (q.w-x.w)*(q.w-x.w);
            q = eq[2]; x = x2; oq[2] = q;
            s += (q.x-x.x)*(q.x-x.x) + (q.y-x.y)*(q.y-x.y) + (q.z-x.z)*(q.z-x.z) + (q.w-x.w)*(q.w-x.w);
            q = eq[3]; x = x3; oq[3] = q;
            s += (q.x-x.x)*(q.x-x.x) + (q.y-x.y)*(q.y-x.y) + (q.z-x.z)*(q.z-x.z) + (q.w-x.w)*(q.w-x.w);
            q = eq[4]; x = x4; oq[4] = q;
            s += (q.x-x.x)*(q.x-x.x) + (q.y-x.y)*(q.y-x.y) + (q.z-x.z)*(q.z-x.z) + (q.w-x.w)*(q.w-x.w);
            q = eq[5]; x = x5; oq[5] = q;
            s += (q.x-x.x)*(q.x-x.x) + (q.y-x.y)*(q.y-x.y) + (q.z-x.z)*(q.z-x.z) + (q.w-x.w)*(q.w-x.w);
            q = eq[6]; x = x6; oq[6] = q;
            s += (q.x-x.x)*(q.x-x.x) + (q.y-x.y)*(q.y-x.y) + (q.z-x.z)*(q.z-x.z) + (q.w-x.w)*(q.w-x.w);
            q = eq[7]; x = x7; oq[7] = q;
            s += (q.x-x.x)*(q.x-x.x) + (q.y-x.y)*(q.y-x.y) + (q.z-x.z)*(q.z-x.z) + (q.w-x.w)*(q.w-x.w);
        }
        out_idx[row] = (float)bi;

        // 64-lane reduction of loss partial
        #pragma unroll
        for (int off = 32; off; off >>= 1) s += __shfl_down(s, off, 64);
        if (lane == 0) ws_partial[blockIdx.x] = s;
    }
}

__global__ void vq_finalize(const float* __restrict__ ws_partial,
                            float* __restrict__ out_loss) {
    float s = 0.0f;
    for (int i = threadIdx.x; i < NBLOCKS; i += 64) s += ws_partial[i];
    #pragma unroll
    for (int off = 32; off; off >>= 1) s += __shfl_down(s, off, 64);
    if (threadIdx.x == 0) *out_loss = s * (1.0f / ((float)NROWS * (float)DIM));
}

extern "C" void kernel_launch(void* const* d_in, const int* in_sizes, int n_in,
                              void* d_out, int out_size, void* d_ws, size_t ws_size,
                              hipStream_t stream) {
    const float* inputs = (const float*)d_in[0];
    const float* emb    = (const float*)d_in[1];
    float* out      = (float*)d_out;
    float* out_q    = out;                          // [32768*32]
    float* out_loss = out + (size_t)NROWS * DIM;    // [1]
    float* out_idx  = out_loss + 1;                 // [32768] as float
    float* wsf      = (float*)d_ws;

    vq_main<<<dim3(NBLOCKS), dim3(WAVES * 64), 0, stream>>>(inputs, emb, out_q, out_idx, wsf);
    vq_finalize<<<dim3(1), dim3(64), 0, stream>>>(wsf, out_loss);
}

// Round 2
// 109.556 us; speedup vs baseline: 2.8521x; 2.8521x over previous
//
#include <hip/hip_runtime.h>

typedef short short8 __attribute__((ext_vector_type(8)));
typedef float f32x4 __attribute__((ext_vector_type(4)));

#define NROWS 32768
#define DIM 32
#define KCODES 8192
#define FLAG_CAP 4096
#define EPS_REL (1.0f/8192.0f)   // 2^-13 per-row flag margin (error bound ~2^-15)

// ws layout (bytes); total ~1.4 MB
#define WS_EHI  0
#define WS_ELO  (512*1024)
#define WS_NORM (1024*1024)
#define WS_IDX  (WS_NORM + 128*1024)
#define WS_LIST (WS_IDX + 128*1024)
#define WS_CNT  (WS_LIST + FLAG_CAP*4)
#define WS_PART (WS_CNT + 64)

__device__ __forceinline__ unsigned short bf16_rne(float v){
    unsigned int u = __float_as_uint(v);
    unsigned int r = (u + 0x7fffu + ((u >> 16) & 1u)) >> 16;
    return (unsigned short)r;
}
__device__ __forceinline__ float bf16_to_f(unsigned short h){
    return __uint_as_float(((unsigned int)h) << 16);
}
__device__ __forceinline__ float dot4(const float4& a, const float4& b){
    return fmaf(a.w, b.w, fmaf(a.z, b.z, fmaf(a.y, b.y, a.x * b.x)));
}

// ---------------- prep: row norms, codebook hi/lo bf16 split, zero counter ---
__global__ __launch_bounds__(256) void vq_prep(
    const float* __restrict__ inputs, const float* __restrict__ emb,
    unsigned short* __restrict__ ehi, unsigned short* __restrict__ elo,
    float* __restrict__ norms, int* __restrict__ cnt)
{
    int tid = blockIdx.x * 256 + threadIdx.x;
    if (tid == 0) *cnt = 0;
    if (tid < NROWS){
        const float4* xr = (const float4*)(inputs + (size_t)tid * DIM);
        float s = 0.f;
        #pragma unroll
        for (int i = 0; i < 8; i++){ float4 v = xr[i]; s += v.x*v.x + v.y*v.y + v.z*v.z + v.w*v.w; }
        norms[tid] = sqrtf(s);
    } else if (tid < NROWS + KCODES){
        int r = tid - NROWS;
        const float* er = emb + (size_t)r * DIM;
        short8* dh = (short8*)(ehi + (size_t)r * DIM);
        short8* dl = (short8*)(elo + (size_t)r * DIM);
        #pragma unroll
        for (int i = 0; i < 4; i++){
            short8 a, b;
            #pragma unroll
            for (int j = 0; j < 8; j++){
                float v = er[i*8 + j];
                unsigned short h = bf16_rne(v);
                a[j] = (short)h;
                b[j] = (short)bf16_rne(v - bf16_to_f(h));
            }
            dh[i] = a; dl[i] = b;
        }
    }
}

// ---------------- main: split-bf16 MFMA argmax with top-2 flagging -----------
// block = 8 waves; wave w scans code slice [w*1024, (w+1)*1024); 64 rows/block.
__global__ __launch_bounds__(512, 4) void vq_main_mfma(
    const float* __restrict__ inputs,
    const unsigned short* __restrict__ ehi,
    const unsigned short* __restrict__ elo,
    const float* __restrict__ norms,
    int* __restrict__ idxws, int* __restrict__ list, int* __restrict__ cnt)
{
    const int L = threadIdx.x & 63;
    const int w = threadIdx.x >> 6;
    const int rowbase = blockIdx.x * 64;

    // A fragments: 4 rowgroups x 16 rows; lane holds row (L&15), k = (L>>4)*8..+8
    short8 ahi[4], alo[4];
    #pragma unroll
    for (int rg = 0; rg < 4; ++rg){
        const float* xr = inputs + (size_t)(rowbase + rg*16 + (L & 15)) * DIM + (L >> 4) * 8;
        float4 p0 = *(const float4*)xr;
        float4 p1 = *(const float4*)(xr + 4);
        float f[8] = {p0.x, p0.y, p0.z, p0.w, p1.x, p1.y, p1.z, p1.w};
        short8 h, l;
        #pragma unroll
        for (int i = 0; i < 8; i++){
            unsigned short hb = bf16_rne(f[i]);
            h[i] = (short)hb;
            l[i] = (short)bf16_rne(f[i] - bf16_to_f(hb));
        }
        ahi[rg] = h; alo[rg] = l;
    }

    float v1[16], v2[16]; int i1[16];
    #pragma unroll
    for (int r = 0; r < 16; r++){ v1[r] = -3.0e38f; v2[r] = -3.0e38f; i1[r] = 0; }

    const int codebase = w * (KCODES / 8);   // 1024 codes per slice, 64 tiles of 16
    const unsigned short* ehp = ehi + (size_t)(codebase + (L & 15)) * DIM + (L >> 4) * 8;
    const unsigned short* elp = elo + (size_t)(codebase + (L & 15)) * DIM + (L >> 4) * 8;

    for (int t = 0; t < 64; ++t){
        short8 bh = *(const short8*)(ehp + t * 16 * DIM);
        short8 bl = *(const short8*)(elp + t * 16 * DIM);
        int kv = codebase + t * 16 + (L & 15);
        #pragma unroll
        for (int rg = 0; rg < 4; ++rg){
            f32x4 acc = {0.f, 0.f, 0.f, 0.f};
            acc = __builtin_amdgcn_mfma_f32_16x16x32_bf16(ahi[rg], bh, acc, 0, 0, 0);
            acc = __builtin_amdgcn_mfma_f32_16x16x32_bf16(ahi[rg], bl, acc, 0, 0, 0);
            acc = __builtin_amdgcn_mfma_f32_16x16x32_bf16(alo[rg], bh, acc, 0, 0, 0);
            #pragma unroll
            for (int q = 0; q < 4; q++){
                int r = rg * 4 + q;
                float sc = acc[q];
                bool gt = sc > v1[r];
                v2[r] = __builtin_amdgcn_fmed3f(sc, v1[r], v2[r]); // second-best update
                v1[r] = gt ? sc : v1[r];
                i1[r] = gt ? kv : i1[r];
            }
        }
    }

    // butterfly over lane&15 (codes dimension), merging (v1,i1) and v2
    #pragma unroll
    for (int m = 1; m < 16; m <<= 1){
        #pragma unroll
        for (int r = 0; r < 16; r++){
            float ov1 = __shfl_xor(v1[r], m, 64);
            int   oi1 = __shfl_xor(i1[r], m, 64);
            float ov2 = __shfl_xor(v2[r], m, 64);
            float mn = fminf(v1[r], ov1);
            v2[r] = fmaxf(fmaxf(v2[r], ov2), mn);
            bool g = ov1 > v1[r];
            v1[r] = g ? ov1 : v1[r];
            i1[r] = g ? oi1 : i1[r];
        }
    }

    __shared__ float sv1[8][64];
    __shared__ float sv2[8][64];
    __shared__ int   si1[8][64];
    if ((L & 15) == 0){
        #pragma unroll
        for (int rg = 0; rg < 4; rg++){
            #pragma unroll
            for (int q = 0; q < 4; q++){
                int rl = rg * 16 + (L >> 4) * 4 + q;   // C row = (lane>>4)*4 + reg
                sv1[w][rl] = v1[rg*4 + q];
                sv2[w][rl] = v2[rg*4 + q];
                si1[w][rl] = i1[rg*4 + q];
            }
        }
    }
    __syncthreads();

    if (threadIdx.x < 64){
        int rl = threadIdx.x;
        float bv1 = -3.0e38f, bv2 = -3.0e38f; int bi = 0;
        #pragma unroll
        for (int s = 0; s < 8; s++){
            float a1 = sv1[s][rl], a2 = sv2[s][rl]; int ai = si1[s][rl];
            float mn = fminf(bv1, a1);
            bv2 = fmaxf(fmaxf(bv2, a2), mn);
            bool g = a1 > bv1;
            bv1 = g ? a1 : bv1;
            bi  = g ? ai : bi;
        }
        int row = rowbase + rl;
        idxws[row] = bi;
        float eps = norms[row] * EPS_REL;
        if (bv1 - bv2 <= eps){
            int pos = atomicAdd(cnt, 1);
            if (pos < FLAG_CAP) list[pos] = row;
        }
    }
}

// ---------------- refine: exact fp32 argmax for flagged rows -----------------
__global__ __launch_bounds__(256) void vq_refine(
    const float* __restrict__ inputs, const float* __restrict__ emb,
    int* __restrict__ idxws, const int* __restrict__ list, const int* __restrict__ cnt)
{
    int n = *cnt; if (n > FLAG_CAP) n = FLAG_CAP;
    __shared__ float sv[4]; __shared__ int si[4];
    for (int j = blockIdx.x; j < n; j += gridDim.x){
        int row = list[j];
        const float4* xr = (const float4*)(inputs + (size_t)row * DIM);
        float4 x0 = xr[0], x1 = xr[1], x2 = xr[2], x3 = xr[3];
        float4 x4 = xr[4], x5 = xr[5], x6 = xr[6], x7 = xr[7];
        float bv = -3.0e38f; int bi = 0x7fffffff;
        for (int c = threadIdx.x; c < KCODES; c += 256){
            const float4* ep = (const float4*)(emb + (size_t)c * DIM);
            float d = dot4(x0, ep[0]) + dot4(x1, ep[1]) + dot4(x2, ep[2]) + dot4(x3, ep[3])
                    + dot4(x4, ep[4]) + dot4(x5, ep[5]) + dot4(x6, ep[6]) + dot4(x7, ep[7]);
            if (d > bv || (d == bv && c < bi)){ bv = d; bi = c; }
        }
        #pragma unroll
        for (int off = 32; off; off >>= 1){
            float ov = __shfl_down(bv, off, 64);
            int   oi = __shfl_down(bi, off, 64);
            if (ov > bv || (ov == bv && oi < bi)){ bv = ov; bi = oi; }
        }
        if ((threadIdx.x & 63) == 0){ sv[threadIdx.x >> 6] = bv; si[threadIdx.x >> 6] = bi; }
        __syncthreads();
        if (threadIdx.x == 0){
            #pragma unroll
            for (int q = 1; q < 4; q++){
                if (sv[q] > bv || (sv[q] == bv && si[q] < bi)){ bv = sv[q]; bi = si[q]; }
            }
            idxws[row] = bi;
        }
        __syncthreads();
    }
}

// ---------------- output: gather quantized rows, indices, loss partials ------
__global__ __launch_bounds__(256) void vq_output(
    const float* __restrict__ inputs, const float* __restrict__ emb,
    const int* __restrict__ idxws,
    float* __restrict__ out_q, float* __restrict__ out_idx, float* __restrict__ part)
{
    int row = blockIdx.x * 256 + threadIdx.x;
    int idx = idxws[row];
    const float4* ep = (const float4*)(emb + (size_t)idx * DIM);
    const float4* xr = (const float4*)(inputs + (size_t)row * DIM);
    float4* oq = (float4*)(out_q + (size_t)row * DIM);
    float s = 0.f;
    #pragma unroll
    for (int i = 0; i < 8; i++){
        float4 q = ep[i], x = xr[i];
        oq[i] = q;
        float dx = q.x - x.x, dy = q.y - x.y, dz = q.z - x.z, dw = q.w - x.w;
        s += dx*dx + dy*dy + dz*dz + dw*dw;
    }
    out_idx[row] = (float)idx;
    #pragma unroll
    for (int off = 32; off; off >>= 1) s += __shfl_down(s, off, 64);
    __shared__ float sp[4];
    if ((threadIdx.x & 63) == 0) sp[threadIdx.x >> 6] = s;
    __syncthreads();
    if (threadIdx.x == 0) part[blockIdx.x] = sp[0] + sp[1] + sp[2] + sp[3];
}

__global__ void vq_loss(const float* __restrict__ part, float* __restrict__ out_loss){
    float s = 0.f;
    for (int i = threadIdx.x; i < 128; i += 64) s += part[i];
    #pragma unroll
    for (int off = 32; off; off >>= 1) s += __shfl_down(s, off, 64);
    if (threadIdx.x == 0) *out_loss = s * (1.0f / ((float)NROWS * (float)DIM));
}

extern "C" void kernel_launch(void* const* d_in, const int* in_sizes, int n_in,
                              void* d_out, int out_size, void* d_ws, size_t ws_size,
                              hipStream_t stream) {
    const float* inputs = (const float*)d_in[0];
    const float* emb    = (const float*)d_in[1];
    float* out      = (float*)d_out;
    float* out_q    = out;                       // [32768*32]
    float* out_loss = out + (size_t)NROWS * DIM; // [1]
    float* out_idx  = out_loss + 1;              // [32768] as float

    char* ws = (char*)d_ws;
    unsigned short* ehi   = (unsigned short*)(ws + WS_EHI);
    unsigned short* elo   = (unsigned short*)(ws + WS_ELO);
    float*          norms = (float*)(ws + WS_NORM);
    int*            idxws = (int*)(ws + WS_IDX);
    int*            list  = (int*)(ws + WS_LIST);
    int*            cnt   = (int*)(ws + WS_CNT);
    float*          part  = (float*)(ws + WS_PART);

    vq_prep     <<<dim3((NROWS + KCODES + 255) / 256), dim3(256), 0, stream>>>(inputs, emb, ehi, elo, norms, cnt);
    vq_main_mfma<<<dim3(NROWS / 64),                   dim3(512), 0, stream>>>(inputs, ehi, elo, norms, idxws, list, cnt);
    vq_refine   <<<dim3(512),                          dim3(256), 0, stream>>>(inputs, emb, idxws, list, cnt);
    vq_output   <<<dim3(NROWS / 256),                  dim3(256), 0, stream>>>(inputs, emb, idxws, out_q, out_idx, part);
    vq_loss     <<<dim3(1),                            dim3(64),  0, stream>>>(part, out_loss);
}

// Round 3
// 103.921 us; speedup vs baseline: 3.0068x; 1.0542x over previous
//
#include <hip/hip_runtime.h>

typedef short short8 __attribute__((ext_vector_type(8)));
typedef float f32x4 __attribute__((ext_vector_type(4)));

#define NROWS 32768
#define DIM 32
#define KCODES 8192
#define FLAG_CAP 4096
#define EPS_REL (1.0f/4096.0f)   // 2^-12 flag margin; packed-score error bound ~2^-14·norm

// ws layout (bytes)
#define WS_EHI  0
#define WS_ELO  (512*1024)
#define WS_IDX  (1024*1024)
#define WS_LIST (WS_IDX + 128*1024)
#define WS_CNT  (WS_LIST + FLAG_CAP*4)
#define WS_PART (WS_CNT + 64)

__device__ __forceinline__ unsigned short bf16_rne(float v){
    unsigned int u = __float_as_uint(v);
    unsigned int r = (u + 0x7fffu + ((u >> 16) & 1u)) >> 16;
    return (unsigned short)r;
}
__device__ __forceinline__ float bf16_to_f(unsigned short h){
    return __uint_as_float(((unsigned int)h) << 16);
}
__device__ __forceinline__ float dot4(const float4& a, const float4& b){
    return fmaf(a.w, b.w, fmaf(a.z, b.z, fmaf(a.y, b.y, a.x * b.x)));
}

// ---------------- prep: codebook hi/lo bf16 split + zero counters ------------
__global__ __launch_bounds__(256) void vq_prep(
    const float* __restrict__ emb,
    unsigned short* __restrict__ ehi, unsigned short* __restrict__ elo,
    int* __restrict__ cnt)
{
    int r = blockIdx.x * 256 + threadIdx.x;   // 0..8191
    if (r < 2) cnt[r] = 0;                    // cnt[0]=flag count, cnt[1]=output ticket
    const float* er = emb + (size_t)r * DIM;
    short8* dh = (short8*)(ehi + (size_t)r * DIM);
    short8* dl = (short8*)(elo + (size_t)r * DIM);
    #pragma unroll
    for (int i = 0; i < 4; i++){
        float4 v0 = *(const float4*)(er + i*8);
        float4 v1 = *(const float4*)(er + i*8 + 4);
        float f[8] = {v0.x, v0.y, v0.z, v0.w, v1.x, v1.y, v1.z, v1.w};
        short8 a, b;
        #pragma unroll
        for (int j = 0; j < 8; j++){
            unsigned short h = bf16_rne(f[j]);
            a[j] = (short)h;
            b[j] = (short)bf16_rne(f[j] - bf16_to_f(h));
        }
        dh[i] = a; dl[i] = b;
    }
}

// ---------------- main: MFMA argmax, packed-uint tracking --------------------
// 8 waves/block; wave w scans codes [w*1024,(w+1)*1024) as 64 tiles of 16.
// 64 rows/block. Bias 2*norm folded into MFMA C-input so scores are positive.
#define PROC(bh, bl, tcs)                                                        \
  {                                                                              \
    unsigned int tcv = (unsigned int)(tcs);                                      \
    _Pragma("unroll")                                                            \
    for (int rg = 0; rg < 4; ++rg){                                              \
      f32x4 acc = __builtin_amdgcn_mfma_f32_16x16x32_bf16(ahi[rg], bh, cbias[rg], 0, 0, 0); \
      acc = __builtin_amdgcn_mfma_f32_16x16x32_bf16(ahi[rg], bl, acc, 0, 0, 0);  \
      acc = __builtin_amdgcn_mfma_f32_16x16x32_bf16(alo[rg], bh, acc, 0, 0, 0);  \
      _Pragma("unroll")                                                          \
      for (int q = 0; q < 4; ++q){                                               \
        unsigned int u = (__float_as_uint(acc[q]) & maskv) | tcv;                \
        int rr = rg * 4 + q;                                                     \
        unsigned int nv2;                                                        \
        asm("v_med3_u32 %0, %1, %2, %3" : "=v"(nv2) : "v"(u), "v"(v1[rr]), "v"(v2[rr])); \
        v2[rr] = nv2;                                                            \
        v1[rr] = (u > v1[rr]) ? u : v1[rr];                                      \
      }                                                                          \
    }                                                                            \
  }

__global__ __launch_bounds__(512, 4) void vq_main_mfma(
    const float* __restrict__ inputs,
    const unsigned short* __restrict__ ehi,
    const unsigned short* __restrict__ elo,
    int* __restrict__ idxws, int* __restrict__ list, int* __restrict__ cnt)
{
    const int L = threadIdx.x & 63;
    const int w = threadIdx.x >> 6;
    const int rowbase = blockIdx.x * 64;

    __shared__ float snorm[64];
    __shared__ unsigned int sv1[8][64][17];
    __shared__ unsigned int sv2[8][64][17];
    __shared__ unsigned int pb1[8][64];
    __shared__ unsigned int pb2[8][64];
    __shared__ int          pbc[8][64];

    // A fragments + per-row norms (all waves load the same 64 rows)
    short8 ahi[4], alo[4];
    #pragma unroll
    for (int rg = 0; rg < 4; ++rg){
        const float* xr = inputs + (size_t)(rowbase + rg*16 + (L & 15)) * DIM + (L >> 4) * 8;
        float4 p0 = *(const float4*)xr;
        float4 p1 = *(const float4*)(xr + 4);
        float f[8] = {p0.x, p0.y, p0.z, p0.w, p1.x, p1.y, p1.z, p1.w};
        short8 h, l;
        #pragma unroll
        for (int i = 0; i < 8; i++){
            unsigned short hb = bf16_rne(f[i]);
            h[i] = (short)hb;
            l[i] = (short)bf16_rne(f[i] - bf16_to_f(hb));
        }
        ahi[rg] = h; alo[rg] = l;
        float s = dot4(p0, p0) + dot4(p1, p1);
        s += __shfl_xor(s, 16, 64);
        s += __shfl_xor(s, 32, 64);
        if (w == 0 && (L >> 4) == 0) snorm[rg*16 + L] = sqrtf(s);
    }
    __syncthreads();

    f32x4 cbias[4];
    #pragma unroll
    for (int rg = 0; rg < 4; ++rg){
        #pragma unroll
        for (int q = 0; q < 4; ++q)
            cbias[rg][q] = 2.0f * snorm[rg*16 + (L >> 4)*4 + q];
    }

    unsigned int maskv = 0xFFFFFFC0u;
    asm("" : "+v"(maskv));   // pin mask in a VGPR so (x & m) | t fuses to v_and_or_b32

    unsigned int v1[16], v2[16];
    #pragma unroll
    for (int r = 0; r < 16; r++){ v1[r] = 0u; v2[r] = 0u; }

    const unsigned short* ehp = ehi + (size_t)(w*1024 + (L & 15)) * DIM + (L >> 4) * 8;
    const unsigned short* elp = elo + (size_t)(w*1024 + (L & 15)) * DIM + (L >> 4) * 8;

    for (int t = 0; t < 64; t += 2){
        short8 bh0 = *(const short8*)(ehp);
        short8 bl0 = *(const short8*)(elp);
        short8 bh1 = *(const short8*)(ehp + 512);
        short8 bl1 = *(const short8*)(elp + 512);
        ehp += 1024; elp += 1024;
        PROC(bh0, bl0, 63 - t);
        PROC(bh1, bl1, 62 - t);
    }

    // dump per-lane (v1,v2) to LDS: sv[w][row][col]
    #pragma unroll
    for (int rg = 0; rg < 4; ++rg){
        #pragma unroll
        for (int q = 0; q < 4; ++q){
            int row = rg*16 + (L >> 4)*4 + q;       // C row = (lane>>4)*4 + reg
            sv1[w][row][L & 15] = v1[rg*4 + q];
            sv2[w][row][L & 15] = v2[rg*4 + q];
        }
    }
    __syncthreads();

    // phase A: thread (row = tid&63, wave-slice = tid>>6) scans 16 cols
    {
        int r = threadIdx.x & 63;
        int s = threadIdx.x >> 6;
        unsigned int b1 = 0u, b2 = 0u; int bc = 0;
        #pragma unroll
        for (int c = 0; c < 16; ++c){
            unsigned int u1 = sv1[s][r][c];
            unsigned int u2 = sv2[s][r][c];
            unsigned int mn = min(b1, u1);
            unsigned int mx = max(b2, u2);
            b2 = max(mn, mx);
            bool g = u1 > b1;
            b1 = g ? u1 : b1;
            bc = g ? c : bc;
        }
        pb1[s][r] = b1; pb2[s][r] = b2; pbc[s][r] = bc;
    }
    __syncthreads();

    // phase B: 64 threads merge 8 wave-slices per row, reconstruct index, flag
    if (threadIdx.x < 64){
        int r = threadIdx.x;
        unsigned int b1 = 0u, b2 = 0u; int bw = 0, bc = 0;
        #pragma unroll
        for (int s = 0; s < 8; ++s){
            unsigned int u1 = pb1[s][r];
            unsigned int u2 = pb2[s][r];
            unsigned int mn = min(b1, u1);
            unsigned int mx = max(b2, u2);
            b2 = max(mn, mx);
            bool g = u1 > b1;
            b1 = g ? u1 : b1;
            bw = g ? s : bw;
            bc = g ? pbc[s][r] : bc;
        }
        int t = 63 - (int)(b1 & 63u);
        int k = bw*1024 + t*16 + bc;
        int row = rowbase + r;
        idxws[row] = k;
        float f1 = __uint_as_float(b1 & 0xFFFFFFC0u);
        float f2 = __uint_as_float(b2 & 0xFFFFFFC0u);
        if (f1 - f2 <= snorm[r] * EPS_REL){
            int pos = atomicAdd(cnt, 1);
            if (pos < FLAG_CAP) list[pos] = row;
        }
    }
}

// ---------------- refine: exact fp32 argmax for flagged rows -----------------
__global__ __launch_bounds__(256) void vq_refine(
    const float* __restrict__ inputs, const float* __restrict__ emb,
    int* __restrict__ idxws, const int* __restrict__ list, const int* __restrict__ cnt)
{
    int n = *cnt; if (n > FLAG_CAP) n = FLAG_CAP;
    __shared__ float sv[4]; __shared__ int si[4];
    for (int j = blockIdx.x; j < n; j += gridDim.x){
        int row = list[j];
        const float4* xr = (const float4*)(inputs + (size_t)row * DIM);
        float4 x0 = xr[0], x1 = xr[1], x2 = xr[2], x3 = xr[3];
        float4 x4 = xr[4], x5 = xr[5], x6 = xr[6], x7 = xr[7];
        float bv = -3.0e38f; int bi = 0x7fffffff;
        for (int c = threadIdx.x; c < KCODES; c += 256){
            const float4* ep = (const float4*)(emb + (size_t)c * DIM);
            float d = dot4(x0, ep[0]) + dot4(x1, ep[1]) + dot4(x2, ep[2]) + dot4(x3, ep[3])
                    + dot4(x4, ep[4]) + dot4(x5, ep[5]) + dot4(x6, ep[6]) + dot4(x7, ep[7]);
            if (d > bv || (d == bv && c < bi)){ bv = d; bi = c; }
        }
        #pragma unroll
        for (int off = 32; off; off >>= 1){
            float ov = __shfl_down(bv, off, 64);
            int   oi = __shfl_down(bi, off, 64);
            if (ov > bv || (ov == bv && oi < bi)){ bv = ov; bi = oi; }
        }
        if ((threadIdx.x & 63) == 0){ sv[threadIdx.x >> 6] = bv; si[threadIdx.x >> 6] = bi; }
        __syncthreads();
        if (threadIdx.x == 0){
            #pragma unroll
            for (int q = 1; q < 4; q++){
                if (sv[q] > bv || (sv[q] == bv && si[q] < bi)){ bv = sv[q]; bi = si[q]; }
            }
            idxws[row] = bi;
        }
        __syncthreads();
    }
}

// ---------------- output: gather + loss partials + last-block finalize -------
__global__ __launch_bounds__(256) void vq_output(
    const float* __restrict__ inputs, const float* __restrict__ emb,
    const int* __restrict__ idxws,
    float* __restrict__ out_q, float* __restrict__ out_idx,
    float* __restrict__ part, int* __restrict__ ticket, float* __restrict__ out_loss)
{
    int row = blockIdx.x * 256 + threadIdx.x;
    int idx = idxws[row];
    const float4* ep = (const float4*)(emb + (size_t)idx * DIM);
    const float4* xr = (const float4*)(inputs + (size_t)row * DIM);
    float4* oq = (float4*)(out_q + (size_t)row * DIM);
    float s = 0.f;
    #pragma unroll
    for (int i = 0; i < 8; i++){
        float4 q = ep[i], x = xr[i];
        oq[i] = q;
        float dx = q.x - x.x, dy = q.y - x.y, dz = q.z - x.z, dw = q.w - x.w;
        s += dx*dx + dy*dy + dz*dz + dw*dw;
    }
    out_idx[row] = (float)idx;
    #pragma unroll
    for (int off = 32; off; off >>= 1) s += __shfl_down(s, off, 64);
    __shared__ float sp[4];
    __shared__ int tkt;
    if ((threadIdx.x & 63) == 0) sp[threadIdx.x >> 6] = s;
    __syncthreads();
    if (threadIdx.x == 0){
        part[blockIdx.x] = sp[0] + sp[1] + sp[2] + sp[3];
        __threadfence();
        tkt = atomicAdd(ticket, 1);
    }
    __syncthreads();
    if (tkt == (NROWS/256) - 1 && threadIdx.x < 64){
        __threadfence();
        float t = 0.f;
        for (int i = threadIdx.x; i < NROWS/256; i += 64) t += part[i];
        #pragma unroll
        for (int off = 32; off; off >>= 1) t += __shfl_down(t, off, 64);
        if (threadIdx.x == 0) *out_loss = t * (1.0f / ((float)NROWS * (float)DIM));
    }
}

extern "C" void kernel_launch(void* const* d_in, const int* in_sizes, int n_in,
                              void* d_out, int out_size, void* d_ws, size_t ws_size,
                              hipStream_t stream) {
    const float* inputs = (const float*)d_in[0];
    const float* emb    = (const float*)d_in[1];
    float* out      = (float*)d_out;
    float* out_q    = out;                       // [32768*32]
    float* out_loss = out + (size_t)NROWS * DIM; // [1]
    float* out_idx  = out_loss + 1;              // [32768] as float

    char* ws = (char*)d_ws;
    unsigned short* ehi   = (unsigned short*)(ws + WS_EHI);
    unsigned short* elo   = (unsigned short*)(ws + WS_ELO);
    int*            idxws = (int*)(ws + WS_IDX);
    int*            list  = (int*)(ws + WS_LIST);
    int*            cnt   = (int*)(ws + WS_CNT);
    float*          part  = (float*)(ws + WS_PART);

    vq_prep     <<<dim3(KCODES/256), dim3(256), 0, stream>>>(emb, ehi, elo, cnt);
    vq_main_mfma<<<dim3(NROWS/64),   dim3(512), 0, stream>>>(inputs, ehi, elo, idxws, list, cnt);
    vq_refine   <<<dim3(256),        dim3(256), 0, stream>>>(inputs, emb, idxws, list, cnt);
    vq_output   <<<dim3(NROWS/256),  dim3(256), 0, stream>>>(inputs, emb, idxws, out_q, out_idx, part, cnt + 1, out_loss);
}